// Round 13
// baseline (158.941 us; speedup 1.0000x reference)
//
#include <hip/hip_runtime.h>
#include <math.h>

#define NQ     4
#define IMGD   28
#define HP     14          // patches per spatial dim
#define NPATCH 196         // 14*14
#define BATCH  2048
#define FEAT   784         // 196*4
#define HID    20
#define NCLS   2

// CRZ ring composed phase integer k(b) = sum_i b_i*(2*b_{(i+1)%4}-1),
// idx = b0*8+b1*4+b2*2+b3 (wire0 = MSB). k = {0,-1,-1,0,-1,-2,0,1,-1,0,-2,1,0,1,1,4}
__device__ __constant__ int d_ktab[16] = {0,-1,-1,0,-1,-2,0,1,-1,0,-2,1,0,1,1,4};

// ---------------------------------------------------------------------------
// Kernel A: one thread per patch, fully scalarized. By-value native trig
// (__sinf/__cosf -> v_sin_f32/v_cos_f32, no pointer out-params) and
// __launch_bounds__(256,8) to force <=64 VGPR -> 8 waves/SIMD.
// ---------------------------------------------------------------------------

// RY 2x2 rotation on amplitude pair (i, j=i|m), complex state
#define RYP(i,j)                                                    \
    { const float t0r = cr##i, t1r = cr##j;                         \
      const float t0i = ci##i, t1i = ci##j;                         \
      cr##i = cy * t0r - sy * t1r;  cr##j = sy * t0r + cy * t1r;    \
      ci##i = cy * t0i - sy * t1i;  ci##j = sy * t0i + cy * t1i; }

#define RY_LAYER()                                                  \
    /* wire 0 (m=8) */ RYP(0,8)  RYP(1,9)  RYP(2,10) RYP(3,11)     \
                       RYP(4,12) RYP(5,13) RYP(6,14) RYP(7,15)     \
    /* wire 1 (m=4) */ RYP(0,4)  RYP(1,5)  RYP(2,6)  RYP(3,7)      \
                       RYP(8,12) RYP(9,13) RYP(10,14) RYP(11,15)   \
    /* wire 2 (m=2) */ RYP(0,2)  RYP(1,3)  RYP(4,6)  RYP(5,7)      \
                       RYP(8,10) RYP(9,11) RYP(12,14) RYP(13,15)   \
    /* wire 3 (m=1) */ RYP(0,1)  RYP(2,3)  RYP(4,5)  RYP(6,7)      \
                       RYP(8,9)  RYP(10,11) RYP(12,13) RYP(14,15)

// full complex diagonal phase multiply: (cr,ci) *= (c_ + i*s_)
#define CRZC(i, c_, s_)                                             \
    { const float nr = cr##i * (c_) - ci##i * (s_);                 \
      ci##i = cr##i * (s_) + ci##i * (c_);  cr##i = nr; }

__global__ __launch_bounds__(256, 8) void patch_z_kernel(
    const float* __restrict__ x,         // [2048,1,28,28]
    const float* __restrict__ ry_theta,  // [1]
    const float* __restrict__ crz_theta, // [1]
    float* __restrict__ z)               // [2048,784] in d_ws
{
    const int p  = blockIdx.x * 256 + threadIdx.x;   // 1568*256 == 401408 exact
    const int b  = p / NPATCH;
    const int r  = p - b * NPATCH;
    const int ph = r / HP, pw = r - ph * HP;

    // Uniform CRZ phases |k| in {1,2,4}: one native sin+cos + double-angle.
    const float hcrz = 0.5f * crz_theta[0];
    const float c1 = __cosf(hcrz), s1 = __sinf(hcrz);
    const float c2 = c1 * c1 - s1 * s1, s2 = 2.f * c1 * s1;
    const float c4 = c2 * c2 - s2 * s2, s4 = 2.f * c2 * s2;
    const float hry = 0.5f * ry_theta[0];
    const float cy = __cosf(hry), sy = __sinf(hry);

    const float* xb = x + (size_t)b * (IMGD * IMGD);
    const float2 p0 = *(const float2*)(xb + (2 * ph)     * IMGD + 2 * pw);
    const float2 p1 = *(const float2*)(xb + (2 * ph + 1) * IMGD + 2 * pw);

    // half-angle trig of the 4 patch pixels (native, by value; |h|<~3 rad)
    const float h0 = 0.5f * p0.x, h1 = 0.5f * p0.y;
    const float h2 = 0.5f * p1.x, h3 = 0.5f * p1.y;
    const float A0 = __cosf(h0), S0  = __sinf(h0);
    const float A1 = __cosf(h1), S1v = __sinf(h1);
    const float A2 = __cosf(h2), S2v = __sinf(h2);
    const float A3 = __cosf(h3), S3v = __sinf(h3);

    // Encoder product state via shared partials (24 mul)
    const float q00 = A0 * A1,  q01 = A0 * S1v, q10 = S0 * A1,  q11 = S0 * S1v;
    const float r00 = A2 * A3,  r01 = A2 * S3v, r10 = S2v * A3, r11 = S2v * S3v;
    float cr0  = q00 * r00, cr1  = q00 * r01, cr2  = q00 * r10, cr3  = q00 * r11;
    float cr4  = q01 * r00, cr5  = q01 * r01, cr6  = q01 * r10, cr7  = q01 * r11;
    float cr8  = q10 * r00, cr9  = q10 * r01, cr10 = q10 * r10, cr11 = q10 * r11;
    float cr12 = q11 * r00, cr13 = q11 * r01, cr14 = q11 * r10, cr15 = q11 * r11;

    // ---- layer 0: CRZ on real state (ci_in = 0): ci = cr*ps, cr *= pc ----
    // k=0 at 0,3,6,9,12 -> identity (ci stays literal 0, folds through RY).
    float ci0 = 0.f, ci3 = 0.f, ci6 = 0.f, ci9 = 0.f, ci12 = 0.f;
    float ci1  = -cr1  * s1;  cr1  *= c1;   // k=-1
    float ci2  = -cr2  * s1;  cr2  *= c1;   // k=-1
    float ci4  = -cr4  * s1;  cr4  *= c1;   // k=-1
    float ci5  = -cr5  * s2;  cr5  *= c2;   // k=-2
    float ci7  =  cr7  * s1;  cr7  *= c1;   // k=+1
    float ci8  = -cr8  * s1;  cr8  *= c1;   // k=-1
    float ci10 = -cr10 * s2;  cr10 *= c2;   // k=-2
    float ci11 =  cr11 * s1;  cr11 *= c1;   // k=+1
    float ci13 =  cr13 * s1;  cr13 *= c1;   // k=+1
    float ci14 =  cr14 * s1;  cr14 *= c1;   // k=+1
    float ci15 =  cr15 * s4;  cr15 *= c4;   // k=+4

    RY_LAYER()

    // ---- layer 1: CRZ full complex (skip k=0 indices) ----
    CRZC(1,  c1, -s1)  CRZC(2,  c1, -s1)  CRZC(4,  c1, -s1)  CRZC(8,  c1, -s1)
    CRZC(5,  c2, -s2)  CRZC(10, c2, -s2)
    CRZC(7,  c1,  s1)  CRZC(11, c1,  s1)  CRZC(13, c1,  s1)  CRZC(14, c1,  s1)
    CRZC(15, c4,  s4)

    RY_LAYER()

    // ---- probabilities + PauliZ sums via shared sum/diff tree ----
#define PROB(i) const float pp##i = cr##i * cr##i + ci##i * ci##i;
    PROB(0) PROB(1) PROB(2) PROB(3) PROB(4) PROB(5) PROB(6) PROB(7)
    PROB(8) PROB(9) PROB(10) PROB(11) PROB(12) PROB(13) PROB(14) PROB(15)
#undef PROB
    const float t01 = pp0 + pp1,   t23 = pp2 + pp3;
    const float t45 = pp4 + pp5,   t67 = pp6 + pp7;
    const float t89 = pp8 + pp9,   tab = pp10 + pp11;
    const float tcd = pp12 + pp13, tef = pp14 + pp15;
    const float u0 = t01 + t23, u1 = t45 + t67, u2 = t89 + tab, u3 = tcd + tef;
    const float z0 = (u0 + u1) - (u2 + u3);                       // wire0: bit3
    const float z1 = (u0 + u2) - (u1 + u3);                       // wire1: bit2
    const float z2 = (t01 - t23) + (t45 - t67) + (t89 - tab) + (tcd - tef); // wire2
    const float z3 = ((pp0 - pp1) + (pp2 - pp3)) + ((pp4 - pp5) + (pp6 - pp7))
                   + ((pp8 - pp9) + (pp10 - pp11)) + ((pp12 - pp13) + (pp14 - pp15)); // wire3

    *((float4*)&z[(size_t)p * 4]) = make_float4(z0, z1, z2, z3);  // coalesced 16B
}

// ---------------------------------------------------------------------------
// Kernel B: one block per image; low VGPR + launch_bounds -> 8 waves/SIMD.
// ---------------------------------------------------------------------------
__global__ __launch_bounds__(256, 8) void fc_kernel(
    const float* __restrict__ z,      // [2048,784] in d_ws
    const float* __restrict__ fc1_w,  // [20,784]
    const float* __restrict__ fc1_b,  // [20]
    const float* __restrict__ fc2_w,  // [2,20]
    const float* __restrict__ fc2_b,  // [2]
    float* __restrict__ out)          // [2048,2]
{
    __shared__ float zs[FEAT];
    __shared__ float hid_s[HID];

    const int tid = threadIdx.x;
    const int b   = blockIdx.x;

    if (tid < NPATCH)  // 196 x float4 = 3136B, coalesced
        ((float4*)zs)[tid] = ((const float4*)(z + (size_t)b * FEAT))[tid];
    __syncthreads();

    const int wave = tid >> 6;
    const int lane = tid & 63;
    #pragma unroll
    for (int hh = 0; hh < 5; ++hh) {
        const int h = wave * 5 + hh;
        const float* wrow = fc1_w + h * FEAT;
        float acc = 0.f;
        #pragma unroll
        for (int f = lane; f < FEAT; f += 64)   // 13 iters, last partial
            acc += zs[f] * wrow[f];
        #pragma unroll
        for (int off = 32; off > 0; off >>= 1)
            acc += __shfl_down(acc, off, 64);
        if (lane == 0) hid_s[h] = acc + fc1_b[h];
    }
    __syncthreads();

    if (tid < NCLS) {
        float acc = fc2_b[tid];
        #pragma unroll
        for (int h = 0; h < HID; ++h)
            acc += fmaxf(hid_s[h], 0.f) * fc2_w[tid * HID + h];
        out[b * NCLS + tid] = acc;
    }
}

// ---------------------------------------------------------------------------
// Fallback: proven fused kernel, used only if ws too small.
// ---------------------------------------------------------------------------
__global__ __launch_bounds__(256) void fused_qnn_kernel(
    const float* __restrict__ x, const float* __restrict__ ry_theta,
    const float* __restrict__ crz_theta, const float* __restrict__ fc1_w,
    const float* __restrict__ fc1_b, const float* __restrict__ fc2_w,
    const float* __restrict__ fc2_b, float* __restrict__ out)
{
    __shared__ float zs[FEAT];
    __shared__ float pc_s[16], ps_s[16];
    __shared__ float rycs[2];
    __shared__ float hid_s[HID];

    const int tid = threadIdx.x;
    const int b   = blockIdx.x;

    if (tid < 16) {
        float sv, cv;
        sincosf(0.5f * crz_theta[0] * (float)d_ktab[tid], &sv, &cv);
        pc_s[tid] = cv; ps_s[tid] = sv;
    } else if (tid == 16) {
        float sv, cv;
        sincosf(0.5f * ry_theta[0], &sv, &cv);
        rycs[0] = cv; rycs[1] = sv;
    }
    __syncthreads();

    if (tid < NPATCH) {
        const int ph = tid / HP, pw = tid % HP;
        const float* xb = x + (size_t)b * (IMGD * IMGD);
        const float2 p0 = *(const float2*)(xb + (2 * ph)     * IMGD + 2 * pw);
        const float2 p1 = *(const float2*)(xb + (2 * ph + 1) * IMGD + 2 * pw);
        const float ang[4] = {p0.x, p0.y, p1.x, p1.y};

        float Ac[4], As[4];
        #pragma unroll
        for (int k = 0; k < 4; ++k) { As[k] = __sinf(0.5f * ang[k]); Ac[k] = __cosf(0.5f * ang[k]); }

        float cr[16], ci[16];
        #pragma unroll
        for (int i = 0; i < 16; ++i) {
            cr[i] = ((i & 8) ? As[0] : Ac[0]) * ((i & 4) ? As[1] : Ac[1]) *
                    ((i & 2) ? As[2] : Ac[2]) * ((i & 1) ? As[3] : Ac[3]);
            ci[i] = 0.0f;
        }

        const float c = rycs[0], s = rycs[1];
        #pragma unroll
        for (int layer = 0; layer < 2; ++layer) {
            #pragma unroll
            for (int i = 0; i < 16; ++i) {
                const float pr = pc_s[i], pi = ps_s[i];
                const float nr = cr[i] * pr - ci[i] * pi;
                const float ni = cr[i] * pi + ci[i] * pr;
                cr[i] = nr; ci[i] = ni;
            }
            #pragma unroll
            for (int w = 0; w < 4; ++w) {
                const int m = 8 >> w;
                #pragma unroll
                for (int i = 0; i < 16; ++i) {
                    if (i & m) continue;
                    const int j = i | m;
                    const float a0r = cr[i], a1r = cr[j];
                    const float a0i = ci[i], a1i = ci[j];
                    cr[i] = c * a0r - s * a1r;
                    cr[j] = s * a0r + c * a1r;
                    ci[i] = c * a0i - s * a1i;
                    ci[j] = s * a0i + c * a1i;
                }
            }
        }

        float z0 = 0.f, z1 = 0.f, z2 = 0.f, z3 = 0.f;
        #pragma unroll
        for (int i = 0; i < 16; ++i) {
            const float pr = cr[i] * cr[i] + ci[i] * ci[i];
            z0 += (i & 8) ? -pr : pr;
            z1 += (i & 4) ? -pr : pr;
            z2 += (i & 2) ? -pr : pr;
            z3 += (i & 1) ? -pr : pr;
        }
        *((float4*)&zs[tid * 4]) = make_float4(z0, z1, z2, z3);
    }
    __syncthreads();

    const int wave = tid >> 6;
    const int lane = tid & 63;
    #pragma unroll
    for (int hh = 0; hh < 5; ++hh) {
        const int h = wave * 5 + hh;
        const float* wrow = fc1_w + h * FEAT;
        float acc = 0.f;
        #pragma unroll
        for (int f = lane; f < FEAT; f += 64)
            acc += zs[f] * wrow[f];
        #pragma unroll
        for (int off = 32; off > 0; off >>= 1)
            acc += __shfl_down(acc, off, 64);
        if (lane == 0) hid_s[h] = acc + fc1_b[h];
    }
    __syncthreads();

    if (tid < NCLS) {
        float acc = fc2_b[tid];
        #pragma unroll
        for (int h = 0; h < HID; ++h)
            acc += fmaxf(hid_s[h], 0.f) * fc2_w[tid * HID + h];
        out[b * NCLS + tid] = acc;
    }
}

extern "C" void kernel_launch(void* const* d_in, const int* in_sizes, int n_in,
                              void* d_out, int out_size, void* d_ws, size_t ws_size,
                              hipStream_t stream) {
    const float* x         = (const float*)d_in[0];
    const float* ry_theta  = (const float*)d_in[1];
    const float* crz_theta = (const float*)d_in[2];
    const float* fc1_w     = (const float*)d_in[3];
    const float* fc1_b     = (const float*)d_in[4];
    const float* fc2_w     = (const float*)d_in[5];
    const float* fc2_b     = (const float*)d_in[6];
    float* out = (float*)d_out;

    const size_t z_bytes = (size_t)BATCH * FEAT * sizeof(float);  // 6.42 MB
    if (ws_size >= z_bytes) {
        float* z = (float*)d_ws;
        patch_z_kernel<<<(BATCH * NPATCH) / 256, 256, 0, stream>>>(
            x, ry_theta, crz_theta, z);
        fc_kernel<<<BATCH, 256, 0, stream>>>(z, fc1_w, fc1_b, fc2_w, fc2_b, out);
    } else {
        fused_qnn_kernel<<<BATCH, 256, 0, stream>>>(
            x, ry_theta, crz_theta, fc1_w, fc1_b, fc2_w, fc2_b, out);
    }
}

// Round 16
// 85.576 us; speedup vs baseline: 1.8573x; 1.8573x over previous
//
#include <hip/hip_runtime.h>
#include <math.h>

#define NQ     4
#define IMGD   28
#define HP     14          // patches per spatial dim
#define NPATCH 196         // 14*14
#define BATCH  2048
#define FEAT   784         // 196*4
#define HID    20
#define NCLS   2
#define BTHR   320         // fc kernel: 5 waves = 20 groups x 16 lanes

// CRZ ring composed phase integer k(b) = sum_i b_i*(2*b_{(i+1)%4}-1),
// idx = b0*8+b1*4+b2*2+b3 (wire0 = MSB). k = {0,-1,-1,0,-1,-2,0,1,-1,0,-2,1,0,1,1,4}
__device__ __constant__ int d_ktab[16] = {0,-1,-1,0,-1,-2,0,1,-1,0,-2,1,0,1,1,4};

// ---------------------------------------------------------------------------
// Kernel A: one thread per patch, scalarized, native by-value trig.
// Plain __launch_bounds__(256) — the (256,8) variant forced VGPR=32 and
// spilled ~220 MB to scratch (round-13 counters: WRITE_SIZE 151 MB,
// FETCH 72 MB, 66 us). Let the allocator pick.
// ---------------------------------------------------------------------------

// RY 2x2 rotation on amplitude pair (i, j=i|m), complex state
#define RYP(i,j)                                                    \
    { const float t0r = cr##i, t1r = cr##j;                         \
      const float t0i = ci##i, t1i = ci##j;                         \
      cr##i = cy * t0r - sy * t1r;  cr##j = sy * t0r + cy * t1r;    \
      ci##i = cy * t0i - sy * t1i;  ci##j = sy * t0i + cy * t1i; }

#define RY_LAYER()                                                  \
    /* wire 0 (m=8) */ RYP(0,8)  RYP(1,9)  RYP(2,10) RYP(3,11)     \
                       RYP(4,12) RYP(5,13) RYP(6,14) RYP(7,15)     \
    /* wire 1 (m=4) */ RYP(0,4)  RYP(1,5)  RYP(2,6)  RYP(3,7)      \
                       RYP(8,12) RYP(9,13) RYP(10,14) RYP(11,15)   \
    /* wire 2 (m=2) */ RYP(0,2)  RYP(1,3)  RYP(4,6)  RYP(5,7)      \
                       RYP(8,10) RYP(9,11) RYP(12,14) RYP(13,15)   \
    /* wire 3 (m=1) */ RYP(0,1)  RYP(2,3)  RYP(4,5)  RYP(6,7)      \
                       RYP(8,9)  RYP(10,11) RYP(12,13) RYP(14,15)

// full complex diagonal phase multiply: (cr,ci) *= (c_ + i*s_)
#define CRZC(i, c_, s_)                                             \
    { const float nr = cr##i * (c_) - ci##i * (s_);                 \
      ci##i = cr##i * (s_) + ci##i * (c_);  cr##i = nr; }

__global__ __launch_bounds__(256) void patch_z_kernel(
    const float* __restrict__ x,         // [2048,1,28,28]
    const float* __restrict__ ry_theta,  // [1]
    const float* __restrict__ crz_theta, // [1]
    float* __restrict__ z)               // [2048,784] in d_ws
{
    const int p  = blockIdx.x * 256 + threadIdx.x;   // 1568*256 == 401408 exact
    const int b  = p / NPATCH;
    const int r  = p - b * NPATCH;
    const int ph = r / HP, pw = r - ph * HP;

    // Uniform CRZ phases |k| in {1,2,4}: one native sin+cos + double-angle.
    const float hcrz = 0.5f * crz_theta[0];
    const float c1 = __cosf(hcrz), s1 = __sinf(hcrz);
    const float c2 = c1 * c1 - s1 * s1, s2 = 2.f * c1 * s1;
    const float c4 = c2 * c2 - s2 * s2, s4 = 2.f * c2 * s2;
    const float hry = 0.5f * ry_theta[0];
    const float cy = __cosf(hry), sy = __sinf(hry);

    const float* xb = x + (size_t)b * (IMGD * IMGD);
    const float2 p0 = *(const float2*)(xb + (2 * ph)     * IMGD + 2 * pw);
    const float2 p1 = *(const float2*)(xb + (2 * ph + 1) * IMGD + 2 * pw);

    // half-angle trig of the 4 patch pixels (native, by value; |h|<~3 rad)
    const float h0 = 0.5f * p0.x, h1 = 0.5f * p0.y;
    const float h2 = 0.5f * p1.x, h3 = 0.5f * p1.y;
    const float A0 = __cosf(h0), S0  = __sinf(h0);
    const float A1 = __cosf(h1), S1v = __sinf(h1);
    const float A2 = __cosf(h2), S2v = __sinf(h2);
    const float A3 = __cosf(h3), S3v = __sinf(h3);

    // Encoder product state via shared partials (24 mul)
    const float q00 = A0 * A1,  q01 = A0 * S1v, q10 = S0 * A1,  q11 = S0 * S1v;
    const float r00 = A2 * A3,  r01 = A2 * S3v, r10 = S2v * A3, r11 = S2v * S3v;
    float cr0  = q00 * r00, cr1  = q00 * r01, cr2  = q00 * r10, cr3  = q00 * r11;
    float cr4  = q01 * r00, cr5  = q01 * r01, cr6  = q01 * r10, cr7  = q01 * r11;
    float cr8  = q10 * r00, cr9  = q10 * r01, cr10 = q10 * r10, cr11 = q10 * r11;
    float cr12 = q11 * r00, cr13 = q11 * r01, cr14 = q11 * r10, cr15 = q11 * r11;

    // ---- layer 0: CRZ on real state (ci_in = 0): ci = cr*ps, cr *= pc ----
    // k=0 at 0,3,6,9,12 -> identity (ci stays literal 0, folds through RY).
    float ci0 = 0.f, ci3 = 0.f, ci6 = 0.f, ci9 = 0.f, ci12 = 0.f;
    float ci1  = -cr1  * s1;  cr1  *= c1;   // k=-1
    float ci2  = -cr2  * s1;  cr2  *= c1;   // k=-1
    float ci4  = -cr4  * s1;  cr4  *= c1;   // k=-1
    float ci5  = -cr5  * s2;  cr5  *= c2;   // k=-2
    float ci7  =  cr7  * s1;  cr7  *= c1;   // k=+1
    float ci8  = -cr8  * s1;  cr8  *= c1;   // k=-1
    float ci10 = -cr10 * s2;  cr10 *= c2;   // k=-2
    float ci11 =  cr11 * s1;  cr11 *= c1;   // k=+1
    float ci13 =  cr13 * s1;  cr13 *= c1;   // k=+1
    float ci14 =  cr14 * s1;  cr14 *= c1;   // k=+1
    float ci15 =  cr15 * s4;  cr15 *= c4;   // k=+4

    RY_LAYER()

    // ---- layer 1: CRZ full complex (skip k=0 indices) ----
    CRZC(1,  c1, -s1)  CRZC(2,  c1, -s1)  CRZC(4,  c1, -s1)  CRZC(8,  c1, -s1)
    CRZC(5,  c2, -s2)  CRZC(10, c2, -s2)
    CRZC(7,  c1,  s1)  CRZC(11, c1,  s1)  CRZC(13, c1,  s1)  CRZC(14, c1,  s1)
    CRZC(15, c4,  s4)

    RY_LAYER()

    // ---- probabilities + PauliZ sums via shared sum/diff tree ----
#define PROB(i) const float pp##i = cr##i * cr##i + ci##i * ci##i;
    PROB(0) PROB(1) PROB(2) PROB(3) PROB(4) PROB(5) PROB(6) PROB(7)
    PROB(8) PROB(9) PROB(10) PROB(11) PROB(12) PROB(13) PROB(14) PROB(15)
#undef PROB
    const float t01 = pp0 + pp1,   t23 = pp2 + pp3;
    const float t45 = pp4 + pp5,   t67 = pp6 + pp7;
    const float t89 = pp8 + pp9,   tab = pp10 + pp11;
    const float tcd = pp12 + pp13, tef = pp14 + pp15;
    const float u0 = t01 + t23, u1 = t45 + t67, u2 = t89 + tab, u3 = tcd + tef;
    const float z0 = (u0 + u1) - (u2 + u3);                       // wire0: bit3
    const float z1 = (u0 + u2) - (u1 + u3);                       // wire1: bit2
    const float z2 = (t01 - t23) + (t45 - t67) + (t89 - tab) + (tcd - tef); // wire2
    const float z3 = ((pp0 - pp1) + (pp2 - pp3)) + ((pp4 - pp5) + (pp6 - pp7))
                   + ((pp8 - pp9) + (pp10 - pp11)) + ((pp12 - pp13) + (pp14 - pp15)); // wire3

    *((float4*)&z[(size_t)p * 4]) = make_float4(z0, z1, z2, z3);  // coalesced 16B
}

// ---------------------------------------------------------------------------
// Kernel B: ledger pins old B at ~38 us (159-55-66). Old: per wave 5
// SEQUENTIAL h-reductions x 6-deep shuffle chains. New: 320 threads =
// 20 groups x 16 lanes, one group per hidden unit -> ONE parallel round,
// shuffle depth 4, float4 dot (784 = 12*64 + 16).
// ---------------------------------------------------------------------------
__global__ __launch_bounds__(BTHR) void fc_kernel(
    const float* __restrict__ z,      // [2048,784] in d_ws
    const float* __restrict__ fc1_w,  // [20,784]
    const float* __restrict__ fc1_b,  // [20]
    const float* __restrict__ fc2_w,  // [2,20]
    const float* __restrict__ fc2_b,  // [2]
    float* __restrict__ out)          // [2048,2]
{
    __shared__ float zs[FEAT];
    __shared__ float hid_s[HID];

    const int tid = threadIdx.x;
    const int b   = blockIdx.x;

    if (tid < NPATCH)  // 196 x float4 = 3136B, coalesced
        ((float4*)zs)[tid] = ((const float4*)(z + (size_t)b * FEAT))[tid];
    __syncthreads();

    const int g = tid >> 4;          // 0..19 = hidden unit
    const int l = tid & 15;          // lane within group
    const float* wrow = fc1_w + g * FEAT;

    // float4 dot: 12 iters x 16 lanes covers 192 float4 = 768 floats
    float4 a4 = make_float4(0.f, 0.f, 0.f, 0.f);
    const float4* z4 = (const float4*)zs;
    const float4* w4 = (const float4*)wrow;
    #pragma unroll
    for (int i = 0; i < 12; ++i) {
        const int f4 = l + (i << 4);
        const float4 zz = z4[f4];
        const float4 ww = w4[f4];
        a4.x += zz.x * ww.x;  a4.y += zz.y * ww.y;
        a4.z += zz.z * ww.z;  a4.w += zz.w * ww.w;
    }
    float acc = (a4.x + a4.y) + (a4.z + a4.w);
    acc += zs[768 + l] * wrow[768 + l];   // scalar tail: 16 floats, 16 lanes

    // 16-lane butterfly reduce (4 steps)
    acc += __shfl_xor(acc, 1, 16);
    acc += __shfl_xor(acc, 2, 16);
    acc += __shfl_xor(acc, 4, 16);
    acc += __shfl_xor(acc, 8, 16);
    if (l == 0) hid_s[g] = acc + fc1_b[g];
    __syncthreads();

    if (tid < NCLS) {
        float o = fc2_b[tid];
        #pragma unroll
        for (int h = 0; h < HID; ++h)
            o += fmaxf(hid_s[h], 0.f) * fc2_w[tid * HID + h];
        out[b * NCLS + tid] = o;
    }
}

// ---------------------------------------------------------------------------
// Fallback: proven fused kernel, used only if ws too small.
// ---------------------------------------------------------------------------
__global__ __launch_bounds__(256) void fused_qnn_kernel(
    const float* __restrict__ x, const float* __restrict__ ry_theta,
    const float* __restrict__ crz_theta, const float* __restrict__ fc1_w,
    const float* __restrict__ fc1_b, const float* __restrict__ fc2_w,
    const float* __restrict__ fc2_b, float* __restrict__ out)
{
    __shared__ float zs[FEAT];
    __shared__ float pc_s[16], ps_s[16];
    __shared__ float rycs[2];
    __shared__ float hid_s[HID];

    const int tid = threadIdx.x;
    const int b   = blockIdx.x;

    if (tid < 16) {
        float sv, cv;
        sincosf(0.5f * crz_theta[0] * (float)d_ktab[tid], &sv, &cv);
        pc_s[tid] = cv; ps_s[tid] = sv;
    } else if (tid == 16) {
        float sv, cv;
        sincosf(0.5f * ry_theta[0], &sv, &cv);
        rycs[0] = cv; rycs[1] = sv;
    }
    __syncthreads();

    if (tid < NPATCH) {
        const int ph = tid / HP, pw = tid % HP;
        const float* xb = x + (size_t)b * (IMGD * IMGD);
        const float2 p0 = *(const float2*)(xb + (2 * ph)     * IMGD + 2 * pw);
        const float2 p1 = *(const float2*)(xb + (2 * ph + 1) * IMGD + 2 * pw);
        const float ang[4] = {p0.x, p0.y, p1.x, p1.y};

        float Ac[4], As[4];
        #pragma unroll
        for (int k = 0; k < 4; ++k) { As[k] = __sinf(0.5f * ang[k]); Ac[k] = __cosf(0.5f * ang[k]); }

        float cr[16], ci[16];
        #pragma unroll
        for (int i = 0; i < 16; ++i) {
            cr[i] = ((i & 8) ? As[0] : Ac[0]) * ((i & 4) ? As[1] : Ac[1]) *
                    ((i & 2) ? As[2] : Ac[2]) * ((i & 1) ? As[3] : Ac[3]);
            ci[i] = 0.0f;
        }

        const float c = rycs[0], s = rycs[1];
        #pragma unroll
        for (int layer = 0; layer < 2; ++layer) {
            #pragma unroll
            for (int i = 0; i < 16; ++i) {
                const float pr = pc_s[i], pi = ps_s[i];
                const float nr = cr[i] * pr - ci[i] * pi;
                const float ni = cr[i] * pi + ci[i] * pr;
                cr[i] = nr; ci[i] = ni;
            }
            #pragma unroll
            for (int w = 0; w < 4; ++w) {
                const int m = 8 >> w;
                #pragma unroll
                for (int i = 0; i < 16; ++i) {
                    if (i & m) continue;
                    const int j = i | m;
                    const float a0r = cr[i], a1r = cr[j];
                    const float a0i = ci[i], a1i = ci[j];
                    cr[i] = c * a0r - s * a1r;
                    cr[j] = s * a0r + c * a1r;
                    ci[i] = c * a0i - s * a1i;
                    ci[j] = s * a0i + c * a1i;
                }
            }
        }

        float z0 = 0.f, z1 = 0.f, z2 = 0.f, z3 = 0.f;
        #pragma unroll
        for (int i = 0; i < 16; ++i) {
            const float pr = cr[i] * cr[i] + ci[i] * ci[i];
            z0 += (i & 8) ? -pr : pr;
            z1 += (i & 4) ? -pr : pr;
            z2 += (i & 2) ? -pr : pr;
            z3 += (i & 1) ? -pr : pr;
        }
        *((float4*)&zs[tid * 4]) = make_float4(z0, z1, z2, z3);
    }
    __syncthreads();

    const int wave = tid >> 6;
    const int lane = tid & 63;
    #pragma unroll
    for (int hh = 0; hh < 5; ++hh) {
        const int h = wave * 5 + hh;
        const float* wrow = fc1_w + h * FEAT;
        float acc = 0.f;
        #pragma unroll
        for (int f = lane; f < FEAT; f += 64)
            acc += zs[f] * wrow[f];
        #pragma unroll
        for (int off = 32; off > 0; off >>= 1)
            acc += __shfl_down(acc, off, 64);
        if (lane == 0) hid_s[h] = acc + fc1_b[h];
    }
    __syncthreads();

    if (tid < NCLS) {
        float acc = fc2_b[tid];
        #pragma unroll
        for (int h = 0; h < HID; ++h)
            acc += fmaxf(hid_s[h], 0.f) * fc2_w[tid * HID + h];
        out[b * NCLS + tid] = acc;
    }
}

extern "C" void kernel_launch(void* const* d_in, const int* in_sizes, int n_in,
                              void* d_out, int out_size, void* d_ws, size_t ws_size,
                              hipStream_t stream) {
    const float* x         = (const float*)d_in[0];
    const float* ry_theta  = (const float*)d_in[1];
    const float* crz_theta = (const float*)d_in[2];
    const float* fc1_w     = (const float*)d_in[3];
    const float* fc1_b     = (const float*)d_in[4];
    const float* fc2_w     = (const float*)d_in[5];
    const float* fc2_b     = (const float*)d_in[6];
    float* out = (float*)d_out;

    const size_t z_bytes = (size_t)BATCH * FEAT * sizeof(float);  // 6.42 MB
    if (ws_size >= z_bytes) {
        float* z = (float*)d_ws;
        patch_z_kernel<<<(BATCH * NPATCH) / 256, 256, 0, stream>>>(
            x, ry_theta, crz_theta, z);
        fc_kernel<<<BATCH, BTHR, 0, stream>>>(z, fc1_w, fc1_b, fc2_w, fc2_b, out);
    } else {
        fused_qnn_kernel<<<BATCH, 256, 0, stream>>>(
            x, ry_theta, crz_theta, fc1_w, fc1_b, fc2_w, fc2_b, out);
    }
}

// Round 17
// 79.883 us; speedup vs baseline: 1.9897x; 1.0713x over previous
//
#include <hip/hip_runtime.h>
#include <math.h>

#define NQ     4
#define IMGD   28
#define HP     14          // patches per spatial dim
#define NPATCH 196         // 14*14
#define BATCH  2048
#define FEAT   784         // 196*4
#define HID    20
#define NCLS   2

// CRZ ring composed phase integer k(b) = sum_i b_i*(2*b_{(i+1)%4}-1),
// idx = b0*8+b1*4+b2*2+b3 (wire0 = MSB). k = {0,-1,-1,0,-1,-2,0,1,-1,0,-2,1,0,1,1,4}
// k=0 at idx 0,3,6,9,12 -> identity phase (hard-coded below).

// RY 2x2 rotation on amplitude pair (i, j=i|m), complex state
#define RYP(i,j)                                                    \
    { const float t0r = cr##i, t1r = cr##j;                         \
      const float t0i = ci##i, t1i = ci##j;                         \
      cr##i = cy * t0r - sy * t1r;  cr##j = sy * t0r + cy * t1r;    \
      ci##i = cy * t0i - sy * t1i;  ci##j = sy * t0i + cy * t1i; }

#define RY_LAYER()                                                  \
    /* wire 0 (m=8) */ RYP(0,8)  RYP(1,9)  RYP(2,10) RYP(3,11)     \
                       RYP(4,12) RYP(5,13) RYP(6,14) RYP(7,15)     \
    /* wire 1 (m=4) */ RYP(0,4)  RYP(1,5)  RYP(2,6)  RYP(3,7)      \
                       RYP(8,12) RYP(9,13) RYP(10,14) RYP(11,15)   \
    /* wire 2 (m=2) */ RYP(0,2)  RYP(1,3)  RYP(4,6)  RYP(5,7)      \
                       RYP(8,10) RYP(9,11) RYP(12,14) RYP(13,15)   \
    /* wire 3 (m=1) */ RYP(0,1)  RYP(2,3)  RYP(4,5)  RYP(6,7)      \
                       RYP(8,9)  RYP(10,11) RYP(12,13) RYP(14,15)

// full complex diagonal phase multiply: (cr,ci) *= (c_ + i*s_)
#define CRZC(i, c_, s_)                                             \
    { const float nr = cr##i * (c_) - ci##i * (s_);                 \
      ci##i = cr##i * (s_) + ci##i * (c_);  cr##i = nr; }

// ---------------------------------------------------------------------------
// FUSED kernel (round 17): one block per image, 256 threads.
//   Phase 0: uniform trig in-register per thread (no LDS table, no barrier).
//   Phase 1: threads 0..195 run the scalarized circuit -> z float4 to LDS.
//            (validated r16: native __sinf/__cosf, no spill at default bounds;
//             do NOT add min-waves launch bound — (256,8) forced VGPR=32 and
//             spilled 220 MB/dispatch, r13 counters.)
//   Phase 2: FC1 as 16 groups x 16 lanes, 2 passes (h=g, then h=16+g on
//            wave 0 only) — float4 dot from LDS + depth-4 butterfly (r16 B).
//   Phase 3: ReLU + FC2 by 2 threads.
// Fusion kills: 2nd launch + drain, z HBM round-trip, B's staging barrier.
// ---------------------------------------------------------------------------
__global__ __launch_bounds__(256) void fused_qnn_kernel(
    const float* __restrict__ x,         // [2048,1,28,28]
    const float* __restrict__ ry_theta,  // [1]
    const float* __restrict__ crz_theta, // [1]
    const float* __restrict__ fc1_w,     // [20,784]
    const float* __restrict__ fc1_b,     // [20]
    const float* __restrict__ fc2_w,     // [2,20]
    const float* __restrict__ fc2_b,     // [2]
    float* __restrict__ out)             // [2048,2]
{
    __shared__ float zs[FEAT];
    __shared__ float hid_s[HID];

    const int tid = threadIdx.x;
    const int b   = blockIdx.x;

    // ---- Phase 0: uniform trig, per-thread in-register (cheap, uniform) ----
    const float hcrz = 0.5f * crz_theta[0];
    const float c1 = __cosf(hcrz), s1 = __sinf(hcrz);
    const float c2 = c1 * c1 - s1 * s1, s2 = 2.f * c1 * s1;
    const float c4 = c2 * c2 - s2 * s2, s4 = 2.f * c2 * s2;
    const float hry = 0.5f * ry_theta[0];
    const float cy = __cosf(hry), sy = __sinf(hry);

    // ---- Phase 1: circuit for one patch per thread (tid < 196) ----
    if (tid < NPATCH) {
        const int ph = tid / HP, pw = tid - ph * HP;
        const float* xb = x + (size_t)b * (IMGD * IMGD);
        const float2 p0 = *(const float2*)(xb + (2 * ph)     * IMGD + 2 * pw);
        const float2 p1 = *(const float2*)(xb + (2 * ph + 1) * IMGD + 2 * pw);

        const float h0 = 0.5f * p0.x, h1 = 0.5f * p0.y;
        const float h2 = 0.5f * p1.x, h3 = 0.5f * p1.y;
        const float A0 = __cosf(h0), S0  = __sinf(h0);
        const float A1 = __cosf(h1), S1v = __sinf(h1);
        const float A2 = __cosf(h2), S2v = __sinf(h2);
        const float A3 = __cosf(h3), S3v = __sinf(h3);

        // Encoder product state via shared partials (24 mul)
        const float q00 = A0 * A1,  q01 = A0 * S1v, q10 = S0 * A1,  q11 = S0 * S1v;
        const float r00 = A2 * A3,  r01 = A2 * S3v, r10 = S2v * A3, r11 = S2v * S3v;
        float cr0  = q00 * r00, cr1  = q00 * r01, cr2  = q00 * r10, cr3  = q00 * r11;
        float cr4  = q01 * r00, cr5  = q01 * r01, cr6  = q01 * r10, cr7  = q01 * r11;
        float cr8  = q10 * r00, cr9  = q10 * r01, cr10 = q10 * r10, cr11 = q10 * r11;
        float cr12 = q11 * r00, cr13 = q11 * r01, cr14 = q11 * r10, cr15 = q11 * r11;

        // layer 0 CRZ on real state: ci = cr*sin, cr *= cos (k=0 -> identity)
        float ci0 = 0.f, ci3 = 0.f, ci6 = 0.f, ci9 = 0.f, ci12 = 0.f;
        float ci1  = -cr1  * s1;  cr1  *= c1;   // k=-1
        float ci2  = -cr2  * s1;  cr2  *= c1;   // k=-1
        float ci4  = -cr4  * s1;  cr4  *= c1;   // k=-1
        float ci5  = -cr5  * s2;  cr5  *= c2;   // k=-2
        float ci7  =  cr7  * s1;  cr7  *= c1;   // k=+1
        float ci8  = -cr8  * s1;  cr8  *= c1;   // k=-1
        float ci10 = -cr10 * s2;  cr10 *= c2;   // k=-2
        float ci11 =  cr11 * s1;  cr11 *= c1;   // k=+1
        float ci13 =  cr13 * s1;  cr13 *= c1;   // k=+1
        float ci14 =  cr14 * s1;  cr14 *= c1;   // k=+1
        float ci15 =  cr15 * s4;  cr15 *= c4;   // k=+4

        RY_LAYER()

        // layer 1 CRZ, full complex (skip k=0 indices)
        CRZC(1,  c1, -s1)  CRZC(2,  c1, -s1)  CRZC(4,  c1, -s1)  CRZC(8,  c1, -s1)
        CRZC(5,  c2, -s2)  CRZC(10, c2, -s2)
        CRZC(7,  c1,  s1)  CRZC(11, c1,  s1)  CRZC(13, c1,  s1)  CRZC(14, c1,  s1)
        CRZC(15, c4,  s4)

        RY_LAYER()

        // probabilities + PauliZ sums via shared sum/diff tree
#define PROB(i) const float pp##i = cr##i * cr##i + ci##i * ci##i;
        PROB(0) PROB(1) PROB(2) PROB(3) PROB(4) PROB(5) PROB(6) PROB(7)
        PROB(8) PROB(9) PROB(10) PROB(11) PROB(12) PROB(13) PROB(14) PROB(15)
#undef PROB
        const float t01 = pp0 + pp1,   t23 = pp2 + pp3;
        const float t45 = pp4 + pp5,   t67 = pp6 + pp7;
        const float t89 = pp8 + pp9,   tab = pp10 + pp11;
        const float tcd = pp12 + pp13, tef = pp14 + pp15;
        const float u0 = t01 + t23, u1 = t45 + t67, u2 = t89 + tab, u3 = tcd + tef;
        const float z0 = (u0 + u1) - (u2 + u3);                       // wire0
        const float z1 = (u0 + u2) - (u1 + u3);                       // wire1
        const float z2 = (t01 - t23) + (t45 - t67) + (t89 - tab) + (tcd - tef);
        const float z3 = ((pp0 - pp1) + (pp2 - pp3)) + ((pp4 - pp5) + (pp6 - pp7))
                       + ((pp8 - pp9) + (pp10 - pp11)) + ((pp12 - pp13) + (pp14 - pp15));

        *((float4*)&zs[tid * 4]) = make_float4(z0, z1, z2, z3);
    }
    __syncthreads();

    // ---- Phase 2: FC1, 16 groups x 16 lanes, 2 passes ----
    const int g = tid >> 4;          // 0..15
    const int l = tid & 15;          // lane within group
    const float4* z4 = (const float4*)zs;

    // pass 0: units 0..15 (all waves); pass 1: units 16..19 (wave 0 only)
    #pragma unroll
    for (int pass = 0; pass < 2; ++pass) {
        const int h = (pass == 0) ? g : (16 + g);
        if (pass == 1 && g >= 4) break;           // tid>=64: whole waves 1-3 exit
        const float* wrow = fc1_w + h * FEAT;
        const float4* w4 = (const float4*)wrow;

        float4 a4 = make_float4(0.f, 0.f, 0.f, 0.f);
        #pragma unroll
        for (int i = 0; i < 12; ++i) {            // 12*16 float4 = 768 floats
            const int f4 = l + (i << 4);
            const float4 zz = z4[f4];
            const float4 ww = w4[f4];
            a4.x += zz.x * ww.x;  a4.y += zz.y * ww.y;
            a4.z += zz.z * ww.z;  a4.w += zz.w * ww.w;
        }
        float acc = (a4.x + a4.y) + (a4.z + a4.w);
        acc += zs[768 + l] * wrow[768 + l];       // 16-float tail

        acc += __shfl_xor(acc, 1, 16);
        acc += __shfl_xor(acc, 2, 16);
        acc += __shfl_xor(acc, 4, 16);
        acc += __shfl_xor(acc, 8, 16);
        if (l == 0) hid_s[h] = acc + fc1_b[h];
    }
    __syncthreads();

    // ---- Phase 3: ReLU + FC2 ----
    if (tid < NCLS) {
        float o = fc2_b[tid];
        #pragma unroll
        for (int h = 0; h < HID; ++h)
            o += fmaxf(hid_s[h], 0.f) * fc2_w[tid * HID + h];
        out[b * NCLS + tid] = o;
    }
}

extern "C" void kernel_launch(void* const* d_in, const int* in_sizes, int n_in,
                              void* d_out, int out_size, void* d_ws, size_t ws_size,
                              hipStream_t stream) {
    const float* x         = (const float*)d_in[0];
    const float* ry_theta  = (const float*)d_in[1];
    const float* crz_theta = (const float*)d_in[2];
    const float* fc1_w     = (const float*)d_in[3];
    const float* fc1_b     = (const float*)d_in[4];
    const float* fc2_w     = (const float*)d_in[5];
    const float* fc2_b     = (const float*)d_in[6];
    float* out = (float*)d_out;

    fused_qnn_kernel<<<BATCH, 256, 0, stream>>>(
        x, ry_theta, crz_theta, fc1_w, fc1_b, fc2_w, fc2_b, out);
}